// Round 4
// baseline (579.966 us; speedup 1.0000x reference)
//
#include <hip/hip_runtime.h>
#include <hip/hip_bf16.h>
#include <cstdint>
#include <cstddef>

// Problem constants (fixed by the reference setup)
#define NE 8
#define NT 16384
#define ND 2048
#define NH 1024

typedef __bf16 bf16;
typedef __bf16 bf16x8 __attribute__((ext_vector_type(8)));
typedef float f32x4 __attribute__((ext_vector_type(4)));
typedef float f32x16 __attribute__((ext_vector_type(16)));

// Address-space casts for global_load_lds.
#define AS1(p) ((__attribute__((address_space(1))) void*)(uintptr_t)(p))
#define AS3(p) ((__attribute__((address_space(3))) void*)(uint32_t)(uintptr_t)(p))
// 16B-wide async global->LDS. HW writes wave-uniform base + lane*16: per-wave
// LDS destinations are exactly contiguous (t*16B); swizzle applied on the
// GLOBAL source address (both-sides-or-neither rule).
#define GLDS16(g, l) __builtin_amdgcn_global_load_lds(AS1(g), AS3(l), 16, 0, 0)

// Counted wait / raw barrier. NO sched_barrier, NO forced lgkm(0): ds_reads
// are plain C++ loads; compiler emits fine-grained lgkmcnt (m141).
#define WAIT_VM(n) asm volatile("s_waitcnt vmcnt(" #n ")" ::: "memory")
#define BAR() asm volatile("s_barrier" ::: "memory")

#define MFMA32(a, b, c) __builtin_amdgcn_mfma_f32_32x32x16_bf16(a, b, c, 0, 0, 0)

// LDS swizzle (BK=64, 128-B rows): 8 slots of 16B per row; physical slot =
// logical ^ (row & 7). Staging thread t writes linear LDS (row=t>>3, phys=t&7)
// from global col-block (t&7)^((t>>3)&7). 32x32x16 reads: lane l needs row
// base+(l&31), logical slot 2s|(l>>5) -> phys = (2s|(l>>5)) ^ (l&7). Exactly 8
// lanes land on each 16B slot (b128 floor) -> conflict-free (measured 0).

__device__ __forceinline__ int expert_of_row(const int* __restrict__ counts, int row0) {
  int e = 0, cum = 0;
#pragma unroll
  for (int i = 0; i < NE; ++i) {
    if (row0 >= cum) e = i;
    cum += counts[i];
  }
  return e;
}

// ---------------- fused f32 -> bf16 conversion (one launch for all 4) -------
__global__ void cvt_all_kernel(const float* __restrict__ x, const float* __restrict__ w1,
                               const float* __restrict__ w3, const float* __restrict__ w2,
                               bf16* __restrict__ xb, bf16* __restrict__ w1b,
                               bf16* __restrict__ w3b, bf16* __restrict__ w2b) {
  const size_t nx = (size_t)NT * ND / 8;       // 4.19M units of 8 elems
  const size_t nw = (size_t)NE * NH * ND / 8;  // 2.10M units
  size_t i = (size_t)blockIdx.x * blockDim.x + threadIdx.x;
  if (i >= nx + 3 * nw) return;
  const float* s;
  bf16* d;
  size_t o;
  if (i < nx)               { s = x;  d = xb;  o = i; }
  else if (i < nx + nw)     { s = w1; d = w1b; o = i - nx; }
  else if (i < nx + 2 * nw) { s = w3; d = w3b; o = i - nx - nw; }
  else                      { s = w2; d = w2b; o = i - nx - 2 * nw; }
  const f32x4* sp = (const f32x4*)s + o * 2;
  f32x4 a = sp[0];
  f32x4 b = sp[1];
  bf16x8 v;
  v[0] = (bf16)a[0]; v[1] = (bf16)a[1]; v[2] = (bf16)a[2]; v[3] = (bf16)a[3];
  v[4] = (bf16)b[0]; v[5] = (bf16)b[1]; v[6] = (bf16)b[2]; v[7] = (bf16)b[3];
  *((bf16x8*)d + o) = v;
}

// ---------------- GEMM1: h = silu(x @ w1^T) * (x @ w3^T), bf16 out -----------
// BM=256, BN=128(dual w1+w3), BK=64. 8 waves (2 row x 4 col); wave owns
// 128x32 of BOTH h1,h3 as 4 m-frags of 32x32x16. 2-deep dbuf, 64 KB/tile
// (A 32K | B1 16K | B3 16K). 4 phases per K-tile (schedule identical to R3):
// Q1=am01*B1, Q2=am01*B3, Q3=am23*B1, Q4=am23*B3; 8 MFMA(32x32x16)/phase.
// Landed-guarantees as R3: vmcnt(2)@P4(k-1) covers A,B1 of tile k;
// vmcnt(2)@P1(k) covers B3(k) before P2 reads it.
__global__ __launch_bounds__(512, 2) void gemm1_kernel(
    const bf16* __restrict__ X, const bf16* __restrict__ W1,
    const bf16* __restrict__ W3, const int* __restrict__ counts,
    bf16* __restrict__ Hb) {
  const int cb = blockIdx.x;   // NH/128 = 8
  const int rb = blockIdx.y;   // NT/256 = 64
  const int t = threadIdx.x;
  const int lane = t & 63;
  const int wave = t >> 6;
  const int wr = wave >> 2;    // 0..1 : 128 rows
  const int wc = wave & 3;     // 0..3 : 32 cols
  const int r31 = lane & 31;
  const int kh = lane >> 5;    // k-half within 16-k slice
  const int l7 = lane & 7;
  int sx[4];
#pragma unroll
  for (int s = 0; s < 4; ++s) sx[s] = (((s << 1) | kh) ^ l7) * 8;

  const int row0 = rb * 256;
  const int e = expert_of_row(counts, row0);

  const bf16* Xe  = X  + (size_t)row0 * ND;
  const bf16* W1e = W1 + (size_t)e * NH * ND + (size_t)cb * 128 * ND;
  const bf16* W3e = W3 + (size_t)e * NH * ND + (size_t)cb * 128 * ND;

  __shared__ __align__(16) bf16 lds[2 * 32768];   // 128 KiB, 64 KB per buffer

  const int t8 = t * 8;
  const int srow8 = t >> 3;                         // 0..63
  const int scol8 = ((t & 7) ^ (srow8 & 7)) * 8;    // pre-swizzled global col
  const bf16* pA  = Xe  + (size_t)srow8 * ND + scol8;
  const bf16* pB1 = W1e + (size_t)srow8 * ND + scol8;
  const bf16* pB3 = W3e + (size_t)srow8 * ND + scol8;

  const int arow  = (wr * 128 + r31) * 64;            // A region base (elems)
  const int b1row = 16384 + (wc * 32 + r31) * 64;     // B1 region
  const int b3row = 24576 + (wc * 32 + r31) * 64;     // B3 region

  f32x16 acc1[4] = {};
  f32x16 acc3[4] = {};

  const int NK = ND / 64;   // 32

  // ---- prologue: stage tile 0 -> buf0; read B1(0) into regs ----
  GLDS16(pA,                     lds + t8);
  GLDS16(pA  + (size_t)64 * ND,  lds + 4096  + t8);
  GLDS16(pA  + (size_t)128 * ND, lds + 8192  + t8);
  GLDS16(pA  + (size_t)192 * ND, lds + 12288 + t8);
  GLDS16(pB1,                    lds + 16384 + t8);
  GLDS16(pB1 + (size_t)64 * ND,  lds + 20480 + t8);
  GLDS16(pB3,                    lds + 24576 + t8);
  GLDS16(pB3 + (size_t)64 * ND,  lds + 28672 + t8);
  WAIT_VM(0);
  BAR();

  bf16x8 b1h[4];
#pragma unroll
  for (int s = 0; s < 4; ++s)
    b1h[s] = *(const bf16x8*)(lds + b1row + sx[s]);

  for (int kt = 0; kt < NK - 1; ++kt) {
    bf16* bufc = lds + (kt & 1) * 32768;
    bf16* nb   = lds + ((kt + 1) & 1) * 32768;   // region safety as R3
    const size_t ko1 = (size_t)(kt + 1) * 64;

    // ---- P1: read am01 (8) | stage A01(k+1) | vmcnt(2) [B3(k) landed] | Q1 --
    bf16x8 am01[2][4];
#pragma unroll
    for (int i = 0; i < 2; ++i)
#pragma unroll
      for (int s = 0; s < 4; ++s)
        am01[i][s] = *(const bf16x8*)(bufc + arow + i * 2048 + sx[s]);
    GLDS16(pA + ko1,                   nb + t8);
    GLDS16(pA + (size_t)64 * ND + ko1, nb + 4096 + t8);
    WAIT_VM(2);
    BAR();
    __builtin_amdgcn_s_setprio(1);
#pragma unroll
    for (int i = 0; i < 2; ++i)
#pragma unroll
      for (int s = 0; s < 4; ++s)
        acc1[i] = MFMA32(am01[i][s], b1h[s], acc1[i]);
    __builtin_amdgcn_s_setprio(0);

    // ---- P2: read B3(k) (4) | stage A23(k+1) | Q2 ----
    bf16x8 b3h[4];
#pragma unroll
    for (int s = 0; s < 4; ++s)
      b3h[s] = *(const bf16x8*)(bufc + b3row + sx[s]);
    GLDS16(pA + (size_t)128 * ND + ko1, nb + 8192  + t8);
    GLDS16(pA + (size_t)192 * ND + ko1, nb + 12288 + t8);
    BAR();
    __builtin_amdgcn_s_setprio(1);
#pragma unroll
    for (int i = 0; i < 2; ++i)
#pragma unroll
      for (int s = 0; s < 4; ++s)
        acc3[i] = MFMA32(am01[i][s], b3h[s], acc3[i]);
    __builtin_amdgcn_s_setprio(0);

    // ---- P3: read am23 (8) | stage B1(k+1) | Q3 ----
    bf16x8 am23[2][4];
#pragma unroll
    for (int i = 0; i < 2; ++i)
#pragma unroll
      for (int s = 0; s < 4; ++s)
        am23[i][s] = *(const bf16x8*)(bufc + arow + (2 + i) * 2048 + sx[s]);
    GLDS16(pB1 + ko1,                   nb + 16384 + t8);
    GLDS16(pB1 + (size_t)64 * ND + ko1, nb + 20480 + t8);
    BAR();
    __builtin_amdgcn_s_setprio(1);
#pragma unroll
    for (int i = 0; i < 2; ++i)
#pragma unroll
      for (int s = 0; s < 4; ++s)
        acc1[2 + i] = MFMA32(am23[i][s], b1h[s], acc1[2 + i]);
    __builtin_amdgcn_s_setprio(0);

    // ---- P4: stage B3(k+1) | vmcnt(2) [A,B1(k+1) landed] | Q4 | read B1(k+1)
    GLDS16(pB3 + ko1,                   nb + 24576 + t8);
    GLDS16(pB3 + (size_t)64 * ND + ko1, nb + 28672 + t8);
    WAIT_VM(2);
    BAR();
    __builtin_amdgcn_s_setprio(1);
#pragma unroll
    for (int i = 0; i < 2; ++i)
#pragma unroll
      for (int s = 0; s < 4; ++s)
        acc3[2 + i] = MFMA32(am23[i][s], b3h[s], acc3[2 + i]);
    __builtin_amdgcn_s_setprio(0);
#pragma unroll
    for (int s = 0; s < 4; ++s)
      b1h[s] = *(const bf16x8*)(nb + b1row + sx[s]);
  }

  // ---- final K-tile: no staging ----
  {
    bf16* bufc = lds + ((NK - 1) & 1) * 32768;
    bf16x8 am[4][4], b3h[4];
#pragma unroll
    for (int i = 0; i < 4; ++i)
#pragma unroll
      for (int s = 0; s < 4; ++s)
        am[i][s] = *(const bf16x8*)(bufc + arow + i * 2048 + sx[s]);
    WAIT_VM(0);   // drain own B3(NK-1) stage; BAR makes it collective
    BAR();
#pragma unroll
    for (int s = 0; s < 4; ++s)
      b3h[s] = *(const bf16x8*)(bufc + b3row + sx[s]);
    __builtin_amdgcn_s_setprio(1);
#pragma unroll
    for (int i = 0; i < 4; ++i)
#pragma unroll
      for (int s = 0; s < 4; ++s) {
        acc1[i] = MFMA32(am[i][s], b1h[s], acc1[i]);
        acc3[i] = MFMA32(am[i][s], b3h[s], acc3[i]);
      }
    __builtin_amdgcn_s_setprio(0);
  }

  // Epilogue: 32x32 C/D layout col=lane&31, row=(reg&3)+8*(reg>>2)+4*(lane>>5).
  const int rbase = row0 + wr * 128 + 4 * kh;
  const int cbase = cb * 128 + wc * 32 + r31;
#pragma unroll
  for (int i = 0; i < 4; ++i)
#pragma unroll
    for (int g = 0; g < 16; ++g) {
      const int row = rbase + i * 32 + (g & 3) + 8 * (g >> 2);
      const float v1 = acc1[i][g];
      const float v3 = acc3[i][g];
      const float hv = (v1 / (1.0f + __expf(-v1))) * v3;
      Hb[(size_t)row * NH + cbase] = (bf16)hv;
    }
}

// ---------------- GEMM2: out = h @ w2^T, f32 out ------------------------------
// BM=256, BN=256, BK=64. 8 waves (2x4); wave owns 128 rows x split cols
// {wc*32..+31} u {128+wc*32..+31} (BL staged P3, BH staged P4 as in R3).
// 4 m-frags x 2 n-frags of 32x32x16. Quads: Q1=am01*BL Q2=am01*BH Q3=am23*BL
// Q4=am23*BH; 8 MFMA/phase.
__global__ __launch_bounds__(512, 2) void gemm2_kernel(
    const bf16* __restrict__ Hb, const bf16* __restrict__ W2,
    const int* __restrict__ counts, float* __restrict__ Out) {
  const int cb = blockIdx.x;   // ND/256 = 8
  const int rb = blockIdx.y;   // NT/256 = 64
  const int t = threadIdx.x;
  const int lane = t & 63;
  const int wave = t >> 6;
  const int wr = wave >> 2;
  const int wc = wave & 3;
  const int r31 = lane & 31;
  const int kh = lane >> 5;
  const int l7 = lane & 7;
  int sx[4];
#pragma unroll
  for (int s = 0; s < 4; ++s) sx[s] = (((s << 1) | kh) ^ l7) * 8;

  const int row0 = rb * 256;
  const int e = expert_of_row(counts, row0);

  const bf16* He  = Hb + (size_t)row0 * NH;
  const bf16* W2e = W2 + (size_t)e * ND * NH + (size_t)cb * 256 * NH;

  __shared__ __align__(16) bf16 lds[2 * 32768];   // 128 KiB

  const int t8 = t * 8;
  const int srow8 = t >> 3;
  const int scol8 = ((t & 7) ^ (srow8 & 7)) * 8;
  const bf16* pA = He  + (size_t)srow8 * NH + scol8;
  const bf16* pB = W2e + (size_t)srow8 * NH + scol8;

  const int arow  = (wr * 128 + r31) * 64;
  const int blrow = 16384 + (wc * 32 + r31) * 64;          // B rows 0..127
  const int bhrow = 16384 + (128 + wc * 32 + r31) * 64;    // B rows 128..255

  f32x16 acc[4][2] = {};   // [m-frag][0=low cols, 1=high cols]

  const int NK = NH / 64;   // 16

  // ---- prologue ----
  GLDS16(pA,                     lds + t8);
  GLDS16(pA + (size_t)64 * NH,   lds + 4096  + t8);
  GLDS16(pA + (size_t)128 * NH,  lds + 8192  + t8);
  GLDS16(pA + (size_t)192 * NH,  lds + 12288 + t8);
  GLDS16(pB,                     lds + 16384 + t8);
  GLDS16(pB + (size_t)64 * NH,   lds + 20480 + t8);
  GLDS16(pB + (size_t)128 * NH,  lds + 24576 + t8);
  GLDS16(pB + (size_t)192 * NH,  lds + 28672 + t8);
  WAIT_VM(0);
  BAR();

  bf16x8 blh[4];
#pragma unroll
  for (int s = 0; s < 4; ++s)
    blh[s] = *(const bf16x8*)(lds + blrow + sx[s]);

  for (int kt = 0; kt < NK - 1; ++kt) {
    bf16* bufc = lds + (kt & 1) * 32768;
    bf16* nb   = lds + ((kt + 1) & 1) * 32768;
    const size_t ko1 = (size_t)(kt + 1) * 64;

    // ---- P1: read am01 | stage A01(k+1) | vmcnt(2) [BH(k) landed] | Q1 ----
    bf16x8 am01[2][4];
#pragma unroll
    for (int i = 0; i < 2; ++i)
#pragma unroll
      for (int s = 0; s < 4; ++s)
        am01[i][s] = *(const bf16x8*)(bufc + arow + i * 2048 + sx[s]);
    GLDS16(pA + ko1,                   nb + t8);
    GLDS16(pA + (size_t)64 * NH + ko1, nb + 4096 + t8);
    WAIT_VM(2);
    BAR();
    __builtin_amdgcn_s_setprio(1);
#pragma unroll
    for (int i = 0; i < 2; ++i)
#pragma unroll
      for (int s = 0; s < 4; ++s)
        acc[i][0] = MFMA32(am01[i][s], blh[s], acc[i][0]);
    __builtin_amdgcn_s_setprio(0);

    // ---- P2: read BH(k) | stage A23(k+1) | Q2 ----
    bf16x8 bhh[4];
#pragma unroll
    for (int s = 0; s < 4; ++s)
      bhh[s] = *(const bf16x8*)(bufc + bhrow + sx[s]);
    GLDS16(pA + (size_t)128 * NH + ko1, nb + 8192  + t8);
    GLDS16(pA + (size_t)192 * NH + ko1, nb + 12288 + t8);
    BAR();
    __builtin_amdgcn_s_setprio(1);
#pragma unroll
    for (int i = 0; i < 2; ++i)
#pragma unroll
      for (int s = 0; s < 4; ++s)
        acc[i][1] = MFMA32(am01[i][s], bhh[s], acc[i][1]);
    __builtin_amdgcn_s_setprio(0);

    // ---- P3: read am23 | stage BL(k+1) | Q3 ----
    bf16x8 am23[2][4];
#pragma unroll
    for (int i = 0; i < 2; ++i)
#pragma unroll
      for (int s = 0; s < 4; ++s)
        am23[i][s] = *(const bf16x8*)(bufc + arow + (2 + i) * 2048 + sx[s]);
    GLDS16(pB + ko1,                   nb + 16384 + t8);
    GLDS16(pB + (size_t)64 * NH + ko1, nb + 20480 + t8);
    BAR();
    __builtin_amdgcn_s_setprio(1);
#pragma unroll
    for (int i = 0; i < 2; ++i)
#pragma unroll
      for (int s = 0; s < 4; ++s)
        acc[2 + i][0] = MFMA32(am23[i][s], blh[s], acc[2 + i][0]);
    __builtin_amdgcn_s_setprio(0);

    // ---- P4: stage BH(k+1) | vmcnt(2) | Q4 | read BL(k+1) ----
    GLDS16(pB + (size_t)128 * NH + ko1, nb + 24576 + t8);
    GLDS16(pB + (size_t)192 * NH + ko1, nb + 28672 + t8);
    WAIT_VM(2);
    BAR();
    __builtin_amdgcn_s_setprio(1);
#pragma unroll
    for (int i = 0; i < 2; ++i)
#pragma unroll
      for (int s = 0; s < 4; ++s)
        acc[2 + i][1] = MFMA32(am23[i][s], bhh[s], acc[2 + i][1]);
    __builtin_amdgcn_s_setprio(0);
#pragma unroll
    for (int s = 0; s < 4; ++s)
      blh[s] = *(const bf16x8*)(nb + blrow + sx[s]);
  }

  // ---- final K-tile ----
  {
    bf16* bufc = lds + ((NK - 1) & 1) * 32768;
    bf16x8 am[4][4], bhh[4];
#pragma unroll
    for (int i = 0; i < 4; ++i)
#pragma unroll
      for (int s = 0; s < 4; ++s)
        am[i][s] = *(const bf16x8*)(bufc + arow + i * 2048 + sx[s]);
    WAIT_VM(0);
    BAR();
#pragma unroll
    for (int s = 0; s < 4; ++s)
      bhh[s] = *(const bf16x8*)(bufc + bhrow + sx[s]);
    __builtin_amdgcn_s_setprio(1);
#pragma unroll
    for (int i = 0; i < 4; ++i)
#pragma unroll
      for (int s = 0; s < 4; ++s) {
        acc[i][0] = MFMA32(am[i][s], blh[s], acc[i][0]);
        acc[i][1] = MFMA32(am[i][s], bhh[s], acc[i][1]);
      }
    __builtin_amdgcn_s_setprio(0);
  }

  // Epilogue: col = cb*256 + wc*32 + j*128 + (lane&31); 32x32 row map.
  const int rbase = row0 + wr * 128 + 4 * kh;
  const int cl = cb * 256 + wc * 32 + r31;
#pragma unroll
  for (int i = 0; i < 4; ++i)
#pragma unroll
    for (int j = 0; j < 2; ++j)
#pragma unroll
      for (int g = 0; g < 16; ++g) {
        const int row = rbase + i * 32 + (g & 3) + 8 * (g >> 2);
        Out[(size_t)row * ND + cl + j * 128] = acc[i][j][g];
      }
}

// -----------------------------------------------------------------------------
extern "C" void kernel_launch(void* const* d_in, const int* in_sizes, int n_in,
                              void* d_out, int out_size, void* d_ws, size_t ws_size,
                              hipStream_t stream) {
  const float* x     = (const float*)d_in[0];
  const int* counts  = (const int*)d_in[1];
  const float* w1    = (const float*)d_in[2];
  const float* w2    = (const float*)d_in[3];
  const float* w3    = (const float*)d_in[4];
  float* out = (float*)d_out;

  char* ws = (char*)d_ws;
  const size_t xN = (size_t)NT * ND;       // 33.5M elems
  const size_t wN = (size_t)NE * NH * ND;  // 16.8M elems per weight
  bf16* xb  = (bf16*)ws;                                  //  64 MiB
  bf16* w1b = (bf16*)(ws + xN * 2);                       // +32 MiB
  bf16* w3b = (bf16*)(ws + xN * 2 + wN * 2);              // +32 MiB
  bf16* w2b = (bf16*)(ws + xN * 2 + 2 * wN * 2);          // +32 MiB
  bf16* hb  = (bf16*)(ws + xN * 2 + 3 * wN * 2);          // +32 MiB (h: T x H bf16)

  {
    const size_t total = (xN + 3 * wN) / 8;   // 10485760 units -> exact grid
    cvt_all_kernel<<<dim3((unsigned)((total + 255) / 256)), dim3(256), 0, stream>>>(
        x, w1, w3, w2, xb, w1b, w3b, w2b);
  }

  gemm1_kernel<<<dim3(NH / 128, NT / 256), dim3(512), 0, stream>>>(xb, w1b, w3b, counts, hb);
  gemm2_kernel<<<dim3(ND / 256, NT / 256), dim3(512), 0, stream>>>(hb, w2b, counts, out);
}